// Round 14
// baseline (151.153 us; speedup 1.0000x reference)
//
#include <hip/hip_runtime.h>
#include <cmath>

// MLDR loss on MI355X, v19: v18 (136.3us, best) + 8-sample boundary table.
//  v18 left k4 latency-bound: VGPR ~100+ and grid 1024x4waves == residency
//  cap (16 waves/CU, zero spare). v19 halves k4's per-thread footprint AND
//  doubles its grid via B8 (8-sample-granular short-state table):
//   K1: raw -> local EMA; snapshot local8 after 8 samples; block scan;
//       wave-exclusive prefix E -> B8[2t]=local8+d^8*E, B8[2t+1]=final
//       (float2 store); long rows Bl stay 16-granular; lane255 -> Eloc.
//   K2: segmented scan -> Y; thread(0,0) zeroes out[0].
//   K3: global long state = Bl + d^16(tid+1)*Yc -> Etab log2-ratios.
//   K4: grid (512,4), SEG=8: carry = B8[hc-1] + (d^8)^hc*Yc; replay 8
//       samples; clamped Etab lerp; block atomicAdd(out).
//  Raw reads NOT duplicated (v16 lesson). B volume 12.6->25 MB (L2/L3).
//  4 dispatches; no fences (v11/v12 lesson); no min-waves bounds (v8/v9).

#define T_LEN    1048576
#define CHUNKS   256
#define CLEN     4096
#define NT1      256
#define SEG1     16       // CLEN / NT1; one 16-gran column per k1 thread
#define COLS     65536    // T_LEN / 16
#define JMAX     65535
#define EPS_CLIP 1e-8f
#define K2SEG    32
#define K2NSEG   8

struct K1Args {
  float d[6];
  float apw[6][7];        // (d^16)^(2^i), i=0..6  (i=6 -> d^1024)
  float a8[6];            // d^8
};
struct K2Args {
  float dL[6];            // d^4096
  float dL32[6];          // d^(4096*32)
};
struct CarryPack {        // one kind, 3 coefs; apw base differs by user:
  float d[3];             //  k3 (long): apw[k][i] = (d^16)^(2^i)
  float apw[3][9];        //  k4 (short): apw[k][i] = (d^8)^(2^i)
};

__device__ __constant__ const int D_SHIFT[3] = {10804, 31972, 63945};

// ---------------- K1: local EMA + block scan -> B8 (8-gran), Bl, Eloc ------
__global__ __launch_bounds__(NT1)
void k1_stage(const float* __restrict__ xp, const float* __restrict__ xt,
              float* __restrict__ Eloc, float* __restrict__ B8,
              float* __restrict__ Bl, int mode, K1Args ka)
{
  int chunk = blockIdx.x, b = blockIdx.y;       // b = which*4 + sig
  int which = b >> 2, sig = b & 3, tid = threadIdx.x;
  long base = (long)chunk * CLEN + (long)tid * SEG1;
  const float* x0 = (which ? xt : xp) + (long)sig * 2 * T_LEN;
  const float* x1 = x0 + T_LEN;

  float S[12];                                  // j = cf*2 + st
#pragma unroll
  for (int j = 0; j < 12; j++) S[j] = 0.f;
  float S8[6];                                  // short-coef state after 8

#pragma unroll
  for (int i = 0; i < SEG1 / 4; i++) {
    if (i == 2) {                               // snapshot local8 (shorts)
#pragma unroll
      for (int k = 0; k < 3; k++) { S8[2*k] = S[4*k]; S8[2*k+1] = S[4*k+1]; }
    }
    float4 a = *(const float4*)(x0 + base + 4*i);
    float4 c4 = *(const float4*)(x1 + base + 4*i);
    float sm, sp, pm, ps;
#define STEP(CMP) \
    sm = a.CMP + c4.CMP; sp = a.CMP - c4.CMP; \
    pm = fmaxf(0.5f * sm * sm, EPS_CLIP); ps = fmaxf(0.5f * sp * sp, EPS_CLIP); \
    _Pragma("unroll") \
    for (int cf = 0; cf < 6; cf++) { \
      S[cf*2+0] = fmaf(ka.d[cf], S[cf*2+0], pm); \
      S[cf*2+1] = fmaf(ka.d[cf], S[cf*2+1], ps); \
    }
    STEP(x) STEP(y) STEP(z) STEP(w)
#undef STEP
  }

  // inclusive chunk-local scan across 256 threads (Hillis-Steele + waves)
  int lane = tid & 63, w = tid >> 6;
#pragma unroll
  for (int i = 0; i < 6; i++) {
#pragma unroll
    for (int j = 0; j < 12; j++) {
      float up = __shfl_up(S[j], 1u << i, 64);
      if (lane >= (1 << i)) S[j] = fmaf(ka.apw[j >> 1][i], up, S[j]);
    }
  }
  // within-wave EXCLUSIVE copy of the short states (for the mid-state)
  float X8[6];
#pragma unroll
  for (int k = 0; k < 3; k++) {
#pragma unroll
    for (int st = 0; st < 2; st++) {
      float xv = __shfl_up(S[4*k+st], 1, 64);
      X8[2*k+st] = (lane == 0) ? 0.f : xv;
    }
  }
  __shared__ float WT[4][12];
  if (lane == 63)
#pragma unroll
    for (int j = 0; j < 12; j++) WT[w][j] = S[j];
  __syncthreads();
  float C[12];
#pragma unroll
  for (int j = 0; j < 12; j++) C[j] = 0.f;
#pragma unroll
  for (int i = 0; i < 4; i++) {
    if (i < w) {
#pragma unroll
      for (int j = 0; j < 12; j++)
        C[j] = fmaf(ka.apw[j >> 1][6], C[j], WT[i][j]);   // A = d^1024
    }
  }
  float alp[6];                                 // a16^(lane+1)
#pragma unroll
  for (int cf = 0; cf < 6; cf++) {
    int e = lane + 1;
    float a = 1.f;
#pragma unroll
    for (int i = 0; i < 7; i++)
      if (e & (1 << i)) a *= ka.apw[cf][i];
    alp[cf] = a;
  }
  float alpE[3];                                // a16^lane for short coefs
#pragma unroll
  for (int k = 0; k < 3; k++) {
    float a = 1.f;
#pragma unroll
    for (int i = 0; i < 6; i++)
      if (lane & (1 << i)) a *= ka.apw[2*k][i];
    alpE[k] = a;
  }
#pragma unroll
  for (int j = 0; j < 12; j++) S[j] = fmaf(alp[j >> 1], C[j], S[j]);

  long col = (long)chunk * (CLEN / SEG1) + tid;
  if (mode & 2) {                               // short rows -> B8 (8-gran)
    long col2 = col * 2;
#pragma unroll
    for (int k = 0; k < 3; k++) {
#pragma unroll
      for (int st = 0; st < 2; st++) {
        float E   = fmaf(alpE[k], C[4*k+st], X8[2*k+st]);   // excl prefix
        float mid = fmaf(ka.a8[2*k], E, S8[2*k+st]);        // state@16t+7
        long row = 4*k + which*2 + st;
        *(float2*)(B8 + row*(8L*COLS) + (long)sig*(2L*COLS) + col2)
            = make_float2(mid, S[4*k+st]);
      }
    }
  }
  if (mode & 1) {                               // long rows (16-gran)
#pragma unroll
    for (int k = 0; k < 3; k++)
#pragma unroll
      for (int st2 = 0; st2 < 2; st2++)
        Bl[(long)(4*k + which*2 + st2) * (4L*COLS) + (long)sig*COLS + col] = S[4*k + 2 + st2];
  }
  if (mode != 2 && tid == NT1 - 1) {            // chunk-end state -> Eloc
#pragma unroll
    for (int cf = 0; cf < 6; cf++)
#pragma unroll
      for (int st = 0; st < 2; st++)
        Eloc[chunk * 96 + (which*8 + sig*2 + st) * 6 + cf] = S[cf*2 + st];
  }
}

// ---------------- K2: segmented scan (96 cols x 8 segments); zero out ------
__global__ __launch_bounds__(768)
void k2_scan(const float* __restrict__ Eloc, float* __restrict__ Y, K2Args ka,
             float* __restrict__ out)
{
  int col = threadIdx.x;        // 0..95
  int seg = threadIdx.y;        // 0..7
  if (col == 0 && seg == 0) out[0] = 0.f;       // zero for k4's atomics
  float dL = ka.dL[col % 6];
  float A  = ka.dL32[col % 6];
  int c0 = seg * K2SEG;

  float yloc[K2SEG];
  float y = 0.f;
#pragma unroll
  for (int i = 0; i < K2SEG; i++) {
    y = fmaf(dL, y, Eloc[(c0 + i) * 96 + col]);
    yloc[i] = y;
  }
  __shared__ float SY[K2NSEG][96];
  SY[seg][col] = y;
  __syncthreads();
  float C = 0.f;
  for (int s = 0; s < seg; s++) C = fmaf(A, C, SY[s][col]);
  float w = dL;
#pragma unroll
  for (int i = 0; i < K2SEG; i++) {
    Y[(c0 + i) * 96 + col] = fmaf(w, C, yloc[i]);
    w *= dL;
  }
}

// ---------------- K3: long table from Bl (unchanged) -----------------------
__global__ __launch_bounds__(256)
void k3_table(const float* __restrict__ Bl, const float* __restrict__ Y,
              float* __restrict__ Etab, CarryPack cp)
{
  int chunk = blockIdx.x, sig = blockIdx.y, tid = threadIdx.x;
  long col = (long)chunk * 256 + tid;

  float Yc[12];
#pragma unroll
  for (int j = 0; j < 12; j++) Yc[j] = 0.f;
  if (chunk > 0) {
    const float* Yp = Y + (chunk - 1) * 96;
    int rm = sig * 2;
#pragma unroll
    for (int k = 0; k < 3; k++) {
      int cf = 2*k + 1;
      Yc[4*k+0] = Yp[rm*6 + cf];       Yc[4*k+1] = Yp[(rm+1)*6 + cf];
      Yc[4*k+2] = Yp[(8+rm)*6 + cf];   Yc[4*k+3] = Yp[(8+rm+1)*6 + cf];
    }
  }
  float fac[3];                                 // a16^(tid+1), tid+1 in [1,256]
#pragma unroll
  for (int k = 0; k < 3; k++) {
    int e = tid + 1;
    float a = 1.f;
#pragma unroll
    for (int i = 0; i < 9; i++)
      if (e & (1 << i)) a *= cp.apw[k][i];
    fac[k] = a;
  }
#pragma unroll
  for (int k = 0; k < 3; k++) {
    float y0 = fmaf(fac[k], Yc[4*k+0], Bl[(long)(4*k+0)*(4L*COLS) + (long)sig*COLS + col]);
    float y1 = fmaf(fac[k], Yc[4*k+1], Bl[(long)(4*k+1)*(4L*COLS) + (long)sig*COLS + col]);
    float y2 = fmaf(fac[k], Yc[4*k+2], Bl[(long)(4*k+2)*(4L*COLS) + (long)sig*COLS + col]);
    float y3 = fmaf(fac[k], Yc[4*k+3], Bl[(long)(4*k+3)*(4L*COLS) + (long)sig*COLS + col]);
    float em = __log2f(y0) - __log2f(y2);       // log2-ratio table
    float es = __log2f(y1) - __log2f(y3);
    long rowm = (long)(k*8 + sig*2);
    Etab[rowm * COLS + col] = em;
    Etab[(rowm+1) * COLS + col] = es;
  }
}

// ---------------- K4: SEG=8 replay from B8 + clamped lerp + atomic ---------
__global__ __launch_bounds__(256)
void k4all(const float* __restrict__ xp, const float* __restrict__ xt,
           const float* __restrict__ Y, const float* __restrict__ B8,
           const float* __restrict__ Etab, CarryPack cp, float* __restrict__ out)
{
  int hb = blockIdx.x, sig = blockIdx.y, tid = threadIdx.x;
  int chunk = hb >> 1;
  int hc = ((hb & 1) << 8) + tid;               // 8-gran col in chunk [0,512)
  long s0 = ((long)chunk * 512 + hc) * 8;       // first sample of this thread

  // carry-in: global short-EMA states at sample s0-1
  float Yc[12];
#pragma unroll
  for (int j = 0; j < 12; j++) Yc[j] = 0.f;
  if (chunk > 0) {
    const float* Yp = Y + (chunk - 1) * 96;
    int rm = sig * 2;
#pragma unroll
    for (int k = 0; k < 3; k++) {
      int cf = 2*k;
      Yc[4*k+0] = Yp[rm*6 + cf];       Yc[4*k+1] = Yp[(rm+1)*6 + cf];
      Yc[4*k+2] = Yp[(8+rm)*6 + cf];   Yc[4*k+3] = Yp[(8+rm+1)*6 + cf];
    }
  }
  float y[12];
  if (hc == 0) {
#pragma unroll
    for (int j = 0; j < 12; j++) y[j] = Yc[j];  // Y[chunk-1] is exact carry
  } else {
    float fac[3];                               // (d^8)^hc, hc in [1,512)
#pragma unroll
    for (int k = 0; k < 3; k++) {
      float a = 1.f;
#pragma unroll
      for (int i = 0; i < 9; i++)
        if (hc & (1 << i)) a *= cp.apw[k][i];
      fac[k] = a;
    }
    long g = (long)chunk * 512 + hc - 1;        // B8 col of state@s0-1
#pragma unroll
    for (int k = 0; k < 3; k++)
#pragma unroll
      for (int q = 0; q < 4; q++)
        y[4*k+q] = fmaf(fac[k], Yc[4*k+q],
                        B8[(long)(4*k+q)*(8L*COLS) + (long)sig*(2L*COLS) + g]);
  }

  // table fetches: single CLAMPED lerp path (v18)
  float tm0[3], tm1[3], tm2[3], ts0[3], ts1[3], ts2[3];
  int ofs[3];
#pragma unroll
  for (int k = 0; k < 3; k++) {
    int q0 = (int)s0 + D_SHIFT[k]; if (q0 >= T_LEN) q0 -= T_LEN;
    int qc = q0 - 15;
    qc = qc < 0 ? 0 : qc;
    const int QCAP = ((JMAX - 2) << 4) + 15;
    qc = qc > QCAP ? QCAP : qc;
    int j0 = qc >> 4;
    ofs[k] = qc & 15;
    const float* Tm = Etab + (long)(k * 8 + sig * 2) * COLS;
    const float* Ts = Tm + COLS;
    tm0[k] = Tm[j0]; tm1[k] = Tm[j0 + 1]; tm2[k] = Tm[j0 + 2];
    ts0[k] = Ts[j0]; ts1[k] = Ts[j0 + 1]; ts2[k] = Ts[j0 + 2];
  }

  const float* p0 = xp + (long)sig * 2 * T_LEN;
  const float* p1 = p0 + T_LEN;
  const float* t0 = xt + (long)sig * 2 * T_LEN;
  const float* t1 = t0 + T_LEN;

  float acc0 = 0.f, acc1 = 0.f;
#pragma unroll
  for (int qt = 0; qt < 2; qt++) {
    float4 a4 = *(const float4*)(p0 + s0 + 4*qt);
    float4 b4 = *(const float4*)(p1 + s0 + 4*qt);
    float4 u4 = *(const float4*)(t0 + s0 + 4*qt);
    float4 w4 = *(const float4*)(t1 + s0 + 4*qt);
#define SAMP(CI, CMP) { \
      const int m = 4*qt + CI; \
      float sm = a4.CMP + b4.CMP, sd = a4.CMP - b4.CMP; \
      float pm = fmaxf(0.5f*sm*sm, EPS_CLIP), ps = fmaxf(0.5f*sd*sd, EPS_CLIP); \
      float em_ = u4.CMP + w4.CMP, ed_ = u4.CMP - w4.CMP; \
      float qm_ = fmaxf(0.5f*em_*em_, EPS_CLIP), qs_ = fmaxf(0.5f*ed_*ed_, EPS_CLIP); \
      _Pragma("unroll") \
      for (int k = 0; k < 3; k++) { \
        float dd = cp.d[k]; \
        y[4*k+0] = fmaf(dd, y[4*k+0], pm);  y[4*k+1] = fmaf(dd, y[4*k+1], ps); \
        y[4*k+2] = fmaf(dd, y[4*k+2], qm_); y[4*k+3] = fmaf(dd, y[4*k+3], qs_); \
        float Dm = __log2f(y[4*k+0]) - __log2f(y[4*k+2]); \
        float Ds = __log2f(y[4*k+1]) - __log2f(y[4*k+3]); \
        int d0 = ofs[k] + m; \
        bool hi = d0 >= 16; \
        float am = hi ? tm1[k] : tm0[k], bm = hi ? tm2[k] : tm1[k]; \
        float as = hi ? ts1[k] : ts0[k], bs = hi ? ts2[k] : ts1[k]; \
        float f = (float)(d0 - (hi ? 16 : 0)) * 0.0625f; \
        float em = fmaf(f, bm - am, am); \
        float es = fmaf(f, bs - as, as); \
        acc0 += fabsf(Dm - em); \
        acc1 += fabsf(Ds - es); \
      } \
    }
    SAMP(0,x) SAMP(1,y) SAMP(2,z) SAMP(3,w)
#undef SAMP
  }

  float acc = acc0 + acc1;
#pragma unroll
  for (int off = 32; off > 0; off >>= 1) acc += __shfl_down(acc, off, 64);
  __shared__ float psum[4];
  int lane = tid & 63, w = tid >> 6;
  if (lane == 0) psum[w] = acc;
  __syncthreads();
  if (tid == 0) {
    const float SCALE = (float)(0.6931471805599453 / (8.0 * 1048576.0));
    float s = psum[0] + psum[1] + psum[2] + psum[3];
    atomicAdd(out, s * SCALE);                  // device-scope; absorbs k5
  }
}

extern "C" void kernel_launch(void* const* d_in, const int* in_sizes, int n_in,
                              void* d_out, int out_size, void* d_ws, size_t ws_size,
                              hipStream_t stream)
{
  (void)in_sizes; (void)n_in; (void)out_size;
  const float* xp = (const float*)d_in[0];
  const float* xt = (const float*)d_in[1];
  float* out = (float*)d_out;
  char* ws = (char*)d_ws;

  const size_t OFF_ELOC = 0;          // 256*96*4 = 98304
  const size_t OFF_Y    = 98304;      // 98304
  const size_t OFF_ETAB = 212992;     // 24*65536*4 = 6 MB, ends 6504448
  const size_t OFF_B8   = 6504448;    // 12*4*131072*4 = 25165824
  const size_t B8_SZ    = 12L * 4 * 2 * COLS * 4;      // 25165824
  const size_t OFF_BL   = OFF_B8 + B8_SZ;              // 31670272
  const size_t BL_SZ    = 12L * 4 * COLS * 4;          // 12582912
  const size_t NEED_FULL = OFF_BL + BL_SZ;             // 44253184 (~42.2 MiB)
  float* Eloc = (float*)(ws + OFF_ELOC);
  float* Ybuf = (float*)(ws + OFF_Y);
  float* Etab = (float*)(ws + OFF_ETAB);
  float* B8   = (float*)(ws + OFF_B8);                 // short states, 8-gran
  float* Blo  = (float*)(ws + OFF_BL);                 // long states, 16-gran

  static const double S_MS[3] = {10.0, 50.0, 100.0};
  static const double L_MS[3] = {500.0, 1500.0, 3000.0};

  K1Args k1a; K2Args k2a; CarryPack cpS, cpL;
  for (int k = 0; k < 3; k++) {
    for (int which = 0; which < 2; which++) {
      int idx = 2 * k + which;
      double ms = which ? L_MS[k] : S_MS[k];
      float cF = (float)(1.0 - std::exp(-2200.0 / (ms * 44100.0)));
      float dF = 1.0f - cF;               // exact fp32 match to reference
      k1a.d[idx] = dF;
      double a16 = std::pow((double)dF, 16.0);
      for (int i = 0; i < 7; i++)
        k1a.apw[idx][i] = (float)std::pow(a16, (double)(1 << i));
      k1a.a8[idx] = (float)std::pow((double)dF, 8.0);
      k2a.dL[idx]   = (float)std::pow((double)dF, (double)CLEN);
      k2a.dL32[idx] = (float)std::pow((double)dF, (double)CLEN * (double)K2SEG);
      CarryPack& cp = which ? cpL : cpS;
      cp.d[k] = dF;
      double aS = which ? a16 : std::pow((double)dF, 8.0);  // k4 uses d^8
      for (int i = 0; i < 9; i++)
        cp.apw[k][i] = (float)std::pow(aS, (double)(1 << i));
    }
  }

  bool full = (ws_size >= NEED_FULL);
  if (full) {
    k1_stage<<<dim3(CHUNKS, 8), NT1, 0, stream>>>(xp, xt, Eloc, B8, Blo, 3, k1a);
    k2_scan<<<dim3(1), dim3(96, K2NSEG), 0, stream>>>(Eloc, Ybuf, k2a, out);
    k3_table<<<dim3(CHUNKS, 4), 256, 0, stream>>>(Blo, Ybuf, Etab, cpL);
    k4all<<<dim3(2*CHUNKS, 4), 256, 0, stream>>>(xp, xt, Ybuf, B8, Etab, cpS, out);
  } else {
    // temporal reuse: Bl aliased onto the B8 region (needs 31.7 MB)
    float* BlA = (float*)(ws + OFF_B8);
    k1_stage<<<dim3(CHUNKS, 8), NT1, 0, stream>>>(xp, xt, Eloc, B8, BlA, 1, k1a);
    k2_scan<<<dim3(1), dim3(96, K2NSEG), 0, stream>>>(Eloc, Ybuf, k2a, out);
    k3_table<<<dim3(CHUNKS, 4), 256, 0, stream>>>(BlA, Ybuf, Etab, cpL);
    k1_stage<<<dim3(CHUNKS, 8), NT1, 0, stream>>>(xp, xt, Eloc, B8, BlA, 2, k1a);
    k4all<<<dim3(2*CHUNKS, 4), 256, 0, stream>>>(xp, xt, Ybuf, B8, Etab, cpS, out);
  }
}

// Round 15
// 131.003 us; speedup vs baseline: 1.1538x; 1.1538x over previous
//
#include <hip/hip_runtime.h>
#include <cmath>

// MLDR loss on MI355X, v20: v18 (136.3us, best) + k3 fused INTO k4 (inline
// table points). v19 post-mortem: SEG=8 doubled per-thread fixed overhead
// (carry+table setup) and B traffic -> regression; k4's shape stays v18
// (SEG=16, NT=256). v20 instead DELETES the k3 dispatch: each k4 thread
// computes its 3 Etab points per coef inline from Bl + Y (bit-identical op
// order to k3: fmaf(a16L^(t'+1), Yc', Bl[g]) -> log2 diff). Adjacent
// threads read adjacent Bl cols -> coalesced/L1. Removes k3 (3.5us) +
// boundary (2.5us) + Etab 6MB write/6MB read (~2us) for ~2us extra in k4.
//  K1: raw -> 16-sample local EMA + inclusive block scan -> Bs,Bl + Eloc.
//  K2: segmented scan -> Y; thread(0,0) zeroes out[0].
//  K4: carry from Bs + inline-table from Bl/Y + clamped lerp + atomicAdd.
//  3 dispatches; no fences (v11/v12); no min-waves bounds (v8/v9).
// Fallback (ws < 30.2 MiB): v18's five-phase temporal-reuse path w/ Etab.

#define T_LEN    1048576
#define CHUNKS   256
#define CLEN     4096
#define NT1      256
#define SEG1     16       // CLEN / NT1; one B column per thread
#define COLS     65536    // T_LEN / 16
#define JMAX     65535
#define EPS_CLIP 1e-8f
#define K2SEG    32
#define K2NSEG   8

struct K1Args {
  float d[6];
  float apw[6][7];        // (d^16)^(2^i), i=0..6  (i=6 -> d^1024)
};
struct K2Args {
  float dL[6];            // d^4096
  float dL32[6];          // d^(4096*32)
};
struct CarryPack {        // one kind (short or long), 3 coefs
  float d[3];
  float apw[3][9];        // (d^16)^(2^i), i=0..8  (i=8 -> d^4096)
};

__device__ __constant__ const int D_SHIFT[3] = {10804, 31972, 63945};

// ---------------- K1: local EMA + inclusive block scan -> B, Eloc ----------
__global__ __launch_bounds__(NT1)
void k1_stage(const float* __restrict__ xp, const float* __restrict__ xt,
              float* __restrict__ Eloc, float* __restrict__ Bs,
              float* __restrict__ Bl, int mode, K1Args ka)
{
  int chunk = blockIdx.x, b = blockIdx.y;       // b = which*4 + sig
  int which = b >> 2, sig = b & 3, tid = threadIdx.x;
  long base = (long)chunk * CLEN + (long)tid * SEG1;
  const float* x0 = (which ? xt : xp) + (long)sig * 2 * T_LEN;
  const float* x1 = x0 + T_LEN;

  float S[12];                                  // j = cf*2 + st
#pragma unroll
  for (int j = 0; j < 12; j++) S[j] = 0.f;

#pragma unroll
  for (int i = 0; i < SEG1 / 4; i++) {
    float4 a = *(const float4*)(x0 + base + 4*i);
    float4 c4 = *(const float4*)(x1 + base + 4*i);
    float sm, sp, pm, ps;
#define STEP(CMP) \
    sm = a.CMP + c4.CMP; sp = a.CMP - c4.CMP; \
    pm = fmaxf(0.5f * sm * sm, EPS_CLIP); ps = fmaxf(0.5f * sp * sp, EPS_CLIP); \
    _Pragma("unroll") \
    for (int cf = 0; cf < 6; cf++) { \
      S[cf*2+0] = fmaf(ka.d[cf], S[cf*2+0], pm); \
      S[cf*2+1] = fmaf(ka.d[cf], S[cf*2+1], ps); \
    }
    STEP(x) STEP(y) STEP(z) STEP(w)
#undef STEP
  }

  // inclusive chunk-local scan across 256 threads (Hillis-Steele + waves)
  int lane = tid & 63, w = tid >> 6;
#pragma unroll
  for (int i = 0; i < 6; i++) {
#pragma unroll
    for (int j = 0; j < 12; j++) {
      float up = __shfl_up(S[j], 1u << i, 64);
      if (lane >= (1 << i)) S[j] = fmaf(ka.apw[j >> 1][i], up, S[j]);
    }
  }
  __shared__ float WT[4][12];
  if (lane == 63)
#pragma unroll
    for (int j = 0; j < 12; j++) WT[w][j] = S[j];
  __syncthreads();
  float C[12];
#pragma unroll
  for (int j = 0; j < 12; j++) C[j] = 0.f;
#pragma unroll
  for (int i = 0; i < 4; i++) {
    if (i < w) {
#pragma unroll
      for (int j = 0; j < 12; j++)
        C[j] = fmaf(ka.apw[j >> 1][6], C[j], WT[i][j]);   // A = d^1024
    }
  }
  float alp[6];                                 // a16^(lane+1)
#pragma unroll
  for (int cf = 0; cf < 6; cf++) {
    int e = lane + 1;
    float a = 1.f;
#pragma unroll
    for (int i = 0; i < 7; i++)
      if (e & (1 << i)) a *= ka.apw[cf][i];
    alp[cf] = a;
  }
#pragma unroll
  for (int j = 0; j < 12; j++) S[j] = fmaf(alp[j >> 1], C[j], S[j]);

  long col = (long)chunk * (CLEN / SEG1) + tid;
  if (mode & 2) {                               // short rows: r = 4k+which*2+st
#pragma unroll
    for (int k = 0; k < 3; k++)
#pragma unroll
      for (int st2 = 0; st2 < 2; st2++)
        Bs[(long)(4*k + which*2 + st2) * (4L*COLS) + (long)sig*COLS + col] = S[4*k + st2];
  }
  if (mode & 1) {                               // long rows
#pragma unroll
    for (int k = 0; k < 3; k++)
#pragma unroll
      for (int st2 = 0; st2 < 2; st2++)
        Bl[(long)(4*k + which*2 + st2) * (4L*COLS) + (long)sig*COLS + col] = S[4*k + 2 + st2];
  }
  if (mode != 2 && tid == NT1 - 1) {            // chunk-end state -> Eloc
#pragma unroll
    for (int cf = 0; cf < 6; cf++)
#pragma unroll
      for (int st = 0; st < 2; st++)
        Eloc[chunk * 96 + (which*8 + sig*2 + st) * 6 + cf] = S[cf*2 + st];
  }
}

// ---------------- K2: segmented scan (96 cols x 8 segments); zero out ------
__global__ __launch_bounds__(768)
void k2_scan(const float* __restrict__ Eloc, float* __restrict__ Y, K2Args ka,
             float* __restrict__ out)
{
  int col = threadIdx.x;        // 0..95
  int seg = threadIdx.y;        // 0..7
  if (col == 0 && seg == 0) out[0] = 0.f;       // zero for k4's atomics
  float dL = ka.dL[col % 6];
  float A  = ka.dL32[col % 6];
  int c0 = seg * K2SEG;

  float yloc[K2SEG];
  float y = 0.f;
#pragma unroll
  for (int i = 0; i < K2SEG; i++) {
    y = fmaf(dL, y, Eloc[(c0 + i) * 96 + col]);
    yloc[i] = y;
  }
  __shared__ float SY[K2NSEG][96];
  SY[seg][col] = y;
  __syncthreads();
  float C = 0.f;
  for (int s = 0; s < seg; s++) C = fmaf(A, C, SY[s][col]);
  float w = dL;
#pragma unroll
  for (int i = 0; i < K2SEG; i++) {
    Y[(c0 + i) * 96 + col] = fmaf(w, C, yloc[i]);
    w *= dL;
  }
}

// ---------------- K3: long table from B (FALLBACK PATH ONLY) ---------------
__global__ __launch_bounds__(256)
void k3_table(const float* __restrict__ Bl, const float* __restrict__ Y,
              float* __restrict__ Etab, CarryPack cp)
{
  int chunk = blockIdx.x, sig = blockIdx.y, tid = threadIdx.x;
  long col = (long)chunk * 256 + tid;

  float Yc[12];
#pragma unroll
  for (int j = 0; j < 12; j++) Yc[j] = 0.f;
  if (chunk > 0) {
    const float* Yp = Y + (chunk - 1) * 96;
    int rm = sig * 2;
#pragma unroll
    for (int k = 0; k < 3; k++) {
      int cf = 2*k + 1;
      Yc[4*k+0] = Yp[rm*6 + cf];       Yc[4*k+1] = Yp[(rm+1)*6 + cf];
      Yc[4*k+2] = Yp[(8+rm)*6 + cf];   Yc[4*k+3] = Yp[(8+rm+1)*6 + cf];
    }
  }
  float fac[3];                                 // a16^(tid+1), tid+1 in [1,256]
#pragma unroll
  for (int k = 0; k < 3; k++) {
    int e = tid + 1;
    float a = 1.f;
#pragma unroll
    for (int i = 0; i < 9; i++)
      if (e & (1 << i)) a *= cp.apw[k][i];
    fac[k] = a;
  }
#pragma unroll
  for (int k = 0; k < 3; k++) {
    float y0 = fmaf(fac[k], Yc[4*k+0], Bl[(long)(4*k+0)*(4L*COLS) + (long)sig*COLS + col]);
    float y1 = fmaf(fac[k], Yc[4*k+1], Bl[(long)(4*k+1)*(4L*COLS) + (long)sig*COLS + col]);
    float y2 = fmaf(fac[k], Yc[4*k+2], Bl[(long)(4*k+2)*(4L*COLS) + (long)sig*COLS + col]);
    float y3 = fmaf(fac[k], Yc[4*k+3], Bl[(long)(4*k+3)*(4L*COLS) + (long)sig*COLS + col]);
    float em = __log2f(y0) - __log2f(y2);       // log2-ratio table
    float es = __log2f(y1) - __log2f(y3);
    long rowm = (long)(k*8 + sig*2);
    Etab[rowm * COLS + col] = em;
    Etab[(rowm+1) * COLS + col] = es;
  }
}

// ---------------- K4 (fallback): replay + Etab clamped lerp + atomic -------
__global__ __launch_bounds__(256)
void k4tab(const float* __restrict__ xp, const float* __restrict__ xt,
           const float* __restrict__ Y, const float* __restrict__ Bs,
           const float* __restrict__ Etab, CarryPack cp, float* __restrict__ out)
{
  int chunk = blockIdx.x, sig = blockIdx.y, tid = threadIdx.x;
  long col = (long)chunk * 256 + tid;
  long base = col * 16;

  float Yc[12];
#pragma unroll
  for (int j = 0; j < 12; j++) Yc[j] = 0.f;
  if (chunk > 0) {
    const float* Yp = Y + (chunk - 1) * 96;
    int rm = sig * 2;
#pragma unroll
    for (int k = 0; k < 3; k++) {
      int cf = 2*k;
      Yc[4*k+0] = Yp[rm*6 + cf];       Yc[4*k+1] = Yp[(rm+1)*6 + cf];
      Yc[4*k+2] = Yp[(8+rm)*6 + cf];   Yc[4*k+3] = Yp[(8+rm+1)*6 + cf];
    }
  }
  float y[12];
  if (tid == 0) {
#pragma unroll
    for (int j = 0; j < 12; j++) y[j] = Yc[j];
  } else {
    float fac[3];
#pragma unroll
    for (int k = 0; k < 3; k++) {
      float a = 1.f;
#pragma unroll
      for (int i = 0; i < 8; i++)
        if (tid & (1 << i)) a *= cp.apw[k][i];
      fac[k] = a;
    }
#pragma unroll
    for (int k = 0; k < 3; k++)
#pragma unroll
      for (int q = 0; q < 4; q++)
        y[4*k+q] = fmaf(fac[k], Yc[4*k+q],
                        Bs[(long)(4*k+q)*(4L*COLS) + (long)sig*COLS + (col-1)]);
  }

  float tm0[3], tm1[3], tm2[3], ts0[3], ts1[3], ts2[3];
  int ofs[3];
#pragma unroll
  for (int k = 0; k < 3; k++) {
    int q0 = (int)base + D_SHIFT[k]; if (q0 >= T_LEN) q0 -= T_LEN;
    int qc = q0 - 15;
    qc = qc < 0 ? 0 : qc;
    const int QCAP = ((JMAX - 2) << 4) + 15;
    qc = qc > QCAP ? QCAP : qc;
    int j0 = qc >> 4;
    ofs[k] = qc & 15;
    const float* Tm = Etab + (long)(k * 8 + sig * 2) * COLS;
    const float* Ts = Tm + COLS;
    tm0[k] = Tm[j0]; tm1[k] = Tm[j0 + 1]; tm2[k] = Tm[j0 + 2];
    ts0[k] = Ts[j0]; ts1[k] = Ts[j0 + 1]; ts2[k] = Ts[j0 + 2];
  }

  const float* p0 = xp + (long)sig * 2 * T_LEN;
  const float* p1 = p0 + T_LEN;
  const float* t0 = xt + (long)sig * 2 * T_LEN;
  const float* t1 = t0 + T_LEN;

  float acc0 = 0.f, acc1 = 0.f;
#pragma unroll
  for (int qt = 0; qt < 4; qt++) {
    float4 a4 = *(const float4*)(p0 + base + 4*qt);
    float4 b4 = *(const float4*)(p1 + base + 4*qt);
    float4 u4 = *(const float4*)(t0 + base + 4*qt);
    float4 w4 = *(const float4*)(t1 + base + 4*qt);
#define SAMP(CI, CMP) { \
      const int m = 4*qt + CI; \
      float sm = a4.CMP + b4.CMP, sd = a4.CMP - b4.CMP; \
      float pm = fmaxf(0.5f*sm*sm, EPS_CLIP), ps = fmaxf(0.5f*sd*sd, EPS_CLIP); \
      float em_ = u4.CMP + w4.CMP, ed_ = u4.CMP - w4.CMP; \
      float qm_ = fmaxf(0.5f*em_*em_, EPS_CLIP), qs_ = fmaxf(0.5f*ed_*ed_, EPS_CLIP); \
      _Pragma("unroll") \
      for (int k = 0; k < 3; k++) { \
        float dd = cp.d[k]; \
        y[4*k+0] = fmaf(dd, y[4*k+0], pm);  y[4*k+1] = fmaf(dd, y[4*k+1], ps); \
        y[4*k+2] = fmaf(dd, y[4*k+2], qm_); y[4*k+3] = fmaf(dd, y[4*k+3], qs_); \
        float Dm = __log2f(y[4*k+0]) - __log2f(y[4*k+2]); \
        float Ds = __log2f(y[4*k+1]) - __log2f(y[4*k+3]); \
        int d0 = ofs[k] + m; \
        bool hi = d0 >= 16; \
        float am = hi ? tm1[k] : tm0[k], bm = hi ? tm2[k] : tm1[k]; \
        float as = hi ? ts1[k] : ts0[k], bs = hi ? ts2[k] : ts1[k]; \
        float f = (float)(d0 - (hi ? 16 : 0)) * 0.0625f; \
        float em = fmaf(f, bm - am, am); \
        float es = fmaf(f, bs - as, as); \
        acc0 += fabsf(Dm - em); \
        acc1 += fabsf(Ds - es); \
      } \
    }
    SAMP(0,x) SAMP(1,y) SAMP(2,z) SAMP(3,w)
#undef SAMP
  }

  float acc = acc0 + acc1;
#pragma unroll
  for (int off = 32; off > 0; off >>= 1) acc += __shfl_down(acc, off, 64);
  __shared__ float psum[4];
  int lane = tid & 63, w = tid >> 6;
  if (lane == 0) psum[w] = acc;
  __syncthreads();
  if (tid == 0) {
    const float SCALE = (float)(0.6931471805599453 / (8.0 * 1048576.0));
    float s = psum[0] + psum[1] + psum[2] + psum[3];
    atomicAdd(out, s * SCALE);
  }
}

// ---------------- K4 (fused): inline table points from Bl/Y (k3 absorbed) --
__global__ __launch_bounds__(256)
void k4fused(const float* __restrict__ xp, const float* __restrict__ xt,
             const float* __restrict__ Y, const float* __restrict__ Bs,
             const float* __restrict__ Bl, CarryPack cpS, CarryPack cpL,
             float* __restrict__ out)
{
  int chunk = blockIdx.x, sig = blockIdx.y, tid = threadIdx.x;
  long col = (long)chunk * 256 + tid;
  long base = col * 16;

  // carry-in: global short-EMA states at sample base-1
  float Yc[12];
#pragma unroll
  for (int j = 0; j < 12; j++) Yc[j] = 0.f;
  if (chunk > 0) {
    const float* Yp = Y + (chunk - 1) * 96;
    int rm = sig * 2;
#pragma unroll
    for (int k = 0; k < 3; k++) {
      int cf = 2*k;
      Yc[4*k+0] = Yp[rm*6 + cf];       Yc[4*k+1] = Yp[(rm+1)*6 + cf];
      Yc[4*k+2] = Yp[(8+rm)*6 + cf];   Yc[4*k+3] = Yp[(8+rm+1)*6 + cf];
    }
  }
  float y[12];
  if (tid == 0) {
#pragma unroll
    for (int j = 0; j < 12; j++) y[j] = Yc[j];  // Y[chunk-1] is exact carry
  } else {
    float fac[3];                               // a16^tid, tid in [1,256)
#pragma unroll
    for (int k = 0; k < 3; k++) {
      float a = 1.f;
#pragma unroll
      for (int i = 0; i < 8; i++)
        if (tid & (1 << i)) a *= cpS.apw[k][i];
      fac[k] = a;
    }
#pragma unroll
    for (int k = 0; k < 3; k++)
#pragma unroll
      for (int q = 0; q < 4; q++)
        y[4*k+q] = fmaf(fac[k], Yc[4*k+q],
                        Bs[(long)(4*k+q)*(4L*COLS) + (long)sig*COLS + (col-1)]);
  }

  // inline Etab points (k3 fused): 3 clamped consecutive points per coef,
  // computed from Bl + Y with k3's exact op order (bit-identical values).
  float tm0[3], tm1[3], tm2[3], ts0[3], ts1[3], ts2[3];
  int ofs[3];
#pragma unroll
  for (int k = 0; k < 3; k++) {
    int q0 = (int)base + D_SHIFT[k]; if (q0 >= T_LEN) q0 -= T_LEN;
    int qc = q0 - 15;
    qc = qc < 0 ? 0 : qc;
    const int QCAP = ((JMAX - 2) << 4) + 15;
    qc = qc > QCAP ? QCAP : qc;
    int j0 = qc >> 4;
    ofs[k] = qc & 15;
    int cf = 2*k + 1;
    float tmv[3], tsv[3];
#pragma unroll
    for (int p = 0; p < 3; p++) {
      int g = j0 + p;                           // <= JMAX by clamp
      int ch = g >> 8, tp = g & 255;
      float Y0 = 0.f, Y1 = 0.f, Y2 = 0.f, Y3 = 0.f;
      if (ch > 0) {
        const float* Yp = Y + (ch - 1) * 96;
        int rm = sig * 2;
        Y0 = Yp[rm*6 + cf];       Y1 = Yp[(rm+1)*6 + cf];
        Y2 = Yp[(8+rm)*6 + cf];   Y3 = Yp[(8+rm+1)*6 + cf];
      }
      int e = tp + 1;
      float a = 1.f;
#pragma unroll
      for (int i = 0; i < 9; i++)
        if (e & (1 << i)) a *= cpL.apw[k][i];
      long bg = (long)sig * COLS + g;
      float w0 = fmaf(a, Y0, Bl[(long)(4*k+0)*(4L*COLS) + bg]);
      float w1 = fmaf(a, Y1, Bl[(long)(4*k+1)*(4L*COLS) + bg]);
      float w2 = fmaf(a, Y2, Bl[(long)(4*k+2)*(4L*COLS) + bg]);
      float w3 = fmaf(a, Y3, Bl[(long)(4*k+3)*(4L*COLS) + bg]);
      tmv[p] = __log2f(w0) - __log2f(w2);
      tsv[p] = __log2f(w1) - __log2f(w3);
    }
    tm0[k] = tmv[0]; tm1[k] = tmv[1]; tm2[k] = tmv[2];
    ts0[k] = tsv[0]; ts1[k] = tsv[1]; ts2[k] = tsv[2];
  }

  const float* p0 = xp + (long)sig * 2 * T_LEN;
  const float* p1 = p0 + T_LEN;
  const float* t0 = xt + (long)sig * 2 * T_LEN;
  const float* t1 = t0 + T_LEN;

  float acc0 = 0.f, acc1 = 0.f;
#pragma unroll
  for (int qt = 0; qt < 4; qt++) {
    float4 a4 = *(const float4*)(p0 + base + 4*qt);
    float4 b4 = *(const float4*)(p1 + base + 4*qt);
    float4 u4 = *(const float4*)(t0 + base + 4*qt);
    float4 w4 = *(const float4*)(t1 + base + 4*qt);
#define SAMP(CI, CMP) { \
      const int m = 4*qt + CI; \
      float sm = a4.CMP + b4.CMP, sd = a4.CMP - b4.CMP; \
      float pm = fmaxf(0.5f*sm*sm, EPS_CLIP), ps = fmaxf(0.5f*sd*sd, EPS_CLIP); \
      float em_ = u4.CMP + w4.CMP, ed_ = u4.CMP - w4.CMP; \
      float qm_ = fmaxf(0.5f*em_*em_, EPS_CLIP), qs_ = fmaxf(0.5f*ed_*ed_, EPS_CLIP); \
      _Pragma("unroll") \
      for (int k = 0; k < 3; k++) { \
        float dd = cpS.d[k]; \
        y[4*k+0] = fmaf(dd, y[4*k+0], pm);  y[4*k+1] = fmaf(dd, y[4*k+1], ps); \
        y[4*k+2] = fmaf(dd, y[4*k+2], qm_); y[4*k+3] = fmaf(dd, y[4*k+3], qs_); \
        float Dm = __log2f(y[4*k+0]) - __log2f(y[4*k+2]); \
        float Ds = __log2f(y[4*k+1]) - __log2f(y[4*k+3]); \
        int d0 = ofs[k] + m; \
        bool hi = d0 >= 16; \
        float am = hi ? tm1[k] : tm0[k], bm = hi ? tm2[k] : tm1[k]; \
        float as = hi ? ts1[k] : ts0[k], bs = hi ? ts2[k] : ts1[k]; \
        float f = (float)(d0 - (hi ? 16 : 0)) * 0.0625f; \
        float em = fmaf(f, bm - am, am); \
        float es = fmaf(f, bs - as, as); \
        acc0 += fabsf(Dm - em); \
        acc1 += fabsf(Ds - es); \
      } \
    }
    SAMP(0,x) SAMP(1,y) SAMP(2,z) SAMP(3,w)
#undef SAMP
  }

  float acc = acc0 + acc1;
#pragma unroll
  for (int off = 32; off > 0; off >>= 1) acc += __shfl_down(acc, off, 64);
  __shared__ float psum[4];
  int lane = tid & 63, w = tid >> 6;
  if (lane == 0) psum[w] = acc;
  __syncthreads();
  if (tid == 0) {
    const float SCALE = (float)(0.6931471805599453 / (8.0 * 1048576.0));
    float s = psum[0] + psum[1] + psum[2] + psum[3];
    atomicAdd(out, s * SCALE);                  // device-scope; absorbs k5
  }
}

extern "C" void kernel_launch(void* const* d_in, const int* in_sizes, int n_in,
                              void* d_out, int out_size, void* d_ws, size_t ws_size,
                              hipStream_t stream)
{
  (void)in_sizes; (void)n_in; (void)out_size;
  const float* xp = (const float*)d_in[0];
  const float* xt = (const float*)d_in[1];
  float* out = (float*)d_out;
  char* ws = (char*)d_ws;

  const size_t OFF_ELOC = 0;          // 256*96*4 = 98304
  const size_t OFF_Y    = 98304;      // 98304
  const size_t OFF_ETAB = 212992;     // 6 MB (fallback only), ends 6504448
  const size_t OFF_B    = 6504448;    // 12 rows = 12.6 MB; 24 rows = 25.2 MB
  const size_t HALF_B   = 12L * 4 * COLS * 4;          // 12582912
  const size_t NEED_FULL = OFF_B + 2 * HALF_B;         // 31670272 (~30.2 MiB)
  float* Eloc = (float*)(ws + OFF_ELOC);
  float* Ybuf = (float*)(ws + OFF_Y);
  float* Etab = (float*)(ws + OFF_ETAB);
  float* Bsh  = (float*)(ws + OFF_B);                  // short rows
  float* Blo  = (float*)(ws + OFF_B + HALF_B);         // long rows (full mode)

  static const double S_MS[3] = {10.0, 50.0, 100.0};
  static const double L_MS[3] = {500.0, 1500.0, 3000.0};

  K1Args k1a; K2Args k2a; CarryPack cpS, cpL;
  for (int k = 0; k < 3; k++) {
    for (int which = 0; which < 2; which++) {
      int idx = 2 * k + which;
      double ms = which ? L_MS[k] : S_MS[k];
      float cF = (float)(1.0 - std::exp(-2200.0 / (ms * 44100.0)));
      float dF = 1.0f - cF;               // exact fp32 match to reference
      k1a.d[idx] = dF;
      double a16 = std::pow((double)dF, 16.0);
      for (int i = 0; i < 7; i++)
        k1a.apw[idx][i] = (float)std::pow(a16, (double)(1 << i));
      k2a.dL[idx]   = (float)std::pow((double)dF, (double)CLEN);
      k2a.dL32[idx] = (float)std::pow((double)dF, (double)CLEN * (double)K2SEG);
      CarryPack& cp = which ? cpL : cpS;
      cp.d[k] = dF;
      for (int i = 0; i < 9; i++)
        cp.apw[k][i] = (float)std::pow(a16, (double)(1 << i));
    }
  }

  bool full = (ws_size >= NEED_FULL);
  if (full) {
    k1_stage<<<dim3(CHUNKS, 8), NT1, 0, stream>>>(xp, xt, Eloc, Bsh, Blo, 3, k1a);
    k2_scan<<<dim3(1), dim3(96, K2NSEG), 0, stream>>>(Eloc, Ybuf, k2a, out);
    k4fused<<<dim3(CHUNKS, 4), 256, 0, stream>>>(xp, xt, Ybuf, Bsh, Blo,
                                                 cpS, cpL, out);
  } else {
    // 19.1 MB budget: v18's proven temporal-reuse path with Etab
    k1_stage<<<dim3(CHUNKS, 8), NT1, 0, stream>>>(xp, xt, Eloc, Bsh, Bsh, 1, k1a);
    k2_scan<<<dim3(1), dim3(96, K2NSEG), 0, stream>>>(Eloc, Ybuf, k2a, out);
    k3_table<<<dim3(CHUNKS, 4), 256, 0, stream>>>(Bsh, Ybuf, Etab, cpL);
    k1_stage<<<dim3(CHUNKS, 8), NT1, 0, stream>>>(xp, xt, Eloc, Bsh, Bsh, 2, k1a);
    k4tab<<<dim3(CHUNKS, 4), 256, 0, stream>>>(xp, xt, Ybuf, Bsh, Etab, cpS, out);
  }
}